// Round 2
// baseline (201.028 us; speedup 1.0000x reference)
//
#include <hip/hip_runtime.h>
#include <math.h>

#define CUT   10          // NDCG_CUTOFF
#define BLOCK 1024
#define NMAX  8192
#define NWAVE (BLOCK / 64)

// Single-block kernel. Key algebra:
//  * disc[i] != 0 only for the 10 top-ranked items by o  =>  delta[i][j] == 0
//    unless i or j is in that top-10 set T. Only ~n*CUT pairs contribute.
//  * For an unordered pair {i,j} with g_i != g_j, summing the two ordered
//    bce terms: bce_ij + bce_ji = 2*softplus(o_lo - o_hi), where "hi" is the
//    member with larger s. (If g_i == g_j, delta == 0, pair contributes 0.)
//  Phase 1: top-10 of o (stable tie-break = smaller index, matching stable
//           jnp.argsort(-o)) via 10 masked argmax passes over an LDS copy.
//  Phase 2: top-10 of s (values only; gains monotone in s) -> idcg.
//  Phase 3: every thread sweeps its strided items j against the 10 top items.
//  Pair {top_t, j} counted once: by thread j if j not in T, else only for
//  slots t < pos(j). delta==0 when o_i == o_j (reference mask).
__global__ __launch_bounds__(BLOCK)
void lambdarank_kernel(const float* __restrict__ og,
                       const float* __restrict__ sg,
                       float* __restrict__ out, int n)
{
    __shared__ float  lds_vals[NMAX];
    __shared__ float  red_v[NWAVE];
    __shared__ int    red_i[NWAVE];
    __shared__ float  top_ov[CUT];   // top-10 o values (desc)
    __shared__ int    top_oi[CUT];   // their indices (rank t item)
    __shared__ float  top_gv[CUT];   // gains of those items
    __shared__ float  sh_idcg;
    __shared__ double wave_part[NWAVE];

    const int tid  = threadIdx.x;
    const int lane = tid & 63;
    const int wid  = tid >> 6;

    // ---------- Phase 1: top-CUT of o ----------
    for (int i = tid; i < n; i += BLOCK) lds_vals[i] = og[i];
    __syncthreads();

    for (int t = 0; t < CUT; ++t) {
        float bv = -INFINITY; int bi = 0x7fffffff;
        for (int i = tid; i < n; i += BLOCK) {
            float v = lds_vals[i];
            if (v > bv || (v == bv && i < bi)) { bv = v; bi = i; }
        }
        for (int off = 32; off > 0; off >>= 1) {
            float ov = __shfl_down(bv, off);
            int   oi = __shfl_down(bi, off);
            if (ov > bv || (ov == bv && oi < bi)) { bv = ov; bi = oi; }
        }
        if (lane == 0) { red_v[wid] = bv; red_i[wid] = bi; }
        __syncthreads();
        if (tid == 0) {
            float fv = red_v[0]; int fi = red_i[0];
            for (int w = 1; w < NWAVE; ++w) {
                if (red_v[w] > fv || (red_v[w] == fv && red_i[w] < fi)) {
                    fv = red_v[w]; fi = red_i[w];
                }
            }
            top_ov[t] = fv; top_oi[t] = fi;
            lds_vals[fi] = -INFINITY;   // mask for next pass
        }
        __syncthreads();
    }

    // ---------- Phase 2: top-CUT of s -> idcg ----------
    for (int i = tid; i < n; i += BLOCK) lds_vals[i] = sg[i];
    __syncthreads();

    float idcg = 0.f;   // accumulated by thread 0 only
    for (int t = 0; t < CUT; ++t) {
        float bv = -INFINITY; int bi = 0x7fffffff;
        for (int i = tid; i < n; i += BLOCK) {
            float v = lds_vals[i];
            if (v > bv || (v == bv && i < bi)) { bv = v; bi = i; }
        }
        for (int off = 32; off > 0; off >>= 1) {
            float ov = __shfl_down(bv, off);
            int   oi = __shfl_down(bi, off);
            if (ov > bv || (ov == bv && oi < bi)) { bv = ov; bi = oi; }
        }
        if (lane == 0) { red_v[wid] = bv; red_i[wid] = bi; }
        __syncthreads();
        if (tid == 0) {
            float fv = red_v[0]; int fi = red_i[0];
            for (int w = 1; w < NWAVE; ++w) {
                if (red_v[w] > fv || (red_v[w] == fv && red_i[w] < fi)) {
                    fv = red_v[w]; fi = red_i[w];
                }
            }
            idcg += (exp2f(fv) - 1.f) / log2f((float)(t + 2));
            lds_vals[fi] = -INFINITY;
        }
        __syncthreads();
    }
    if (tid == 0) sh_idcg = idcg;
    if (tid < CUT) top_gv[tid] = exp2f(sg[top_oi[tid]]) - 1.f;
    __syncthreads();

    // ---------- Phase 3: pair sweep ----------
    const float inv_idcg = 1.f / sh_idcg;
    double acc = 0.0;
    for (int j = tid; j < n; j += BLOCK) {
        float oj = og[j];
        float gj = exp2f(sg[j]) - 1.f;
        int pos = CUT;                     // CUT => not in top set
        #pragma unroll
        for (int t = 0; t < CUT; ++t) if (top_oi[t] == j) pos = t;
        float discj = (pos < CUT) ? 1.f / log2f((float)(pos + 2)) : 0.f;
        const int kmax = pos;              // j in T: only t < pos (count once)
        for (int t = 0; t < kmax; ++t) {
            float oi = top_ov[t];
            if (oi == oj) continue;        // reference masks o_i == o_j pairs
            float dg = top_gv[t] - gj;     // sign(dg) == sign(s_t - s_j)
            if (dg == 0.f) continue;       // delta == 0
            float disci = 1.f / log2f((float)(t + 2));
            float delta = fabsf(dg * (disci - discj)) * inv_idcg;
            // bce_ij + bce_ji = 2*softplus(o_lo - o_hi), hi = larger-s member
            float darg  = (dg > 0.f) ? (oj - oi) : (oi - oj);
            float sp    = fmaxf(darg, 0.f) + log1pf(expf(-fabsf(darg)));
            acc += (double)(delta * (2.f * sp));
        }
    }

    // ---------- block reduce ----------
    for (int off = 32; off > 0; off >>= 1) acc += __shfl_down(acc, off);
    if (lane == 0) wave_part[wid] = acc;
    __syncthreads();
    if (tid == 0) {
        double tot = 0.0;
        for (int w = 0; w < NWAVE; ++w) tot += wave_part[w];
        out[0] = (float)(tot / (double)n);
    }
}

extern "C" void kernel_launch(void* const* d_in, const int* in_sizes, int n_in,
                              void* d_out, int out_size, void* d_ws, size_t ws_size,
                              hipStream_t stream) {
    const float* o = (const float*)d_in[0];
    const float* s = (const float*)d_in[1];
    float* out = (float*)d_out;
    int n = in_sizes[0];                  // 8192 (outputs is (N,1))
    lambdarank_kernel<<<dim3(1), dim3(BLOCK), 0, stream>>>(o, s, out, n);
}

// Round 4
// 108.699 us; speedup vs baseline: 1.8494x; 1.8494x over previous
//
#include <hip/hip_runtime.h>
#include <math.h>
#include <stdint.h>

#define CUT    10            // NDCG_CUTOFF
#define BLOCK  1024
#define HALF   512
#define NMAX   8192
#define PERT   (NMAX / HALF) // 16 items/thread within a group
#define NWAVE  (BLOCK / 64)
#define GWAVES 8             // waves per group
#define JPT    (NMAX / BLOCK)

// Sortable key: monotone u32 of float in high bits, ~index in low bits.
// max(key) == max value, ties broken toward SMALLER index (stable argsort(-o)).
__device__ __forceinline__ uint64_t pack_key(float v, int i) {
    uint32_t fb = __float_as_uint(v);
    uint32_t k  = (fb & 0x80000000u) ? ~fb : (fb | 0x80000000u);
    return ((uint64_t)k << 32) | (uint32_t)~(uint32_t)i;
}
__device__ __forceinline__ float key_val(uint64_t key) {
    uint32_t k  = (uint32_t)(key >> 32);
    uint32_t fb = (k & 0x80000000u) ? (k & 0x7FFFFFFFu) : ~k;
    return __uint_as_float(fb);
}
__device__ __forceinline__ int key_idx(uint64_t key) {
    return (int)~(uint32_t)key;
}

// Single block. Waves 0-7: top-10 of o (stable). Waves 8-15: top-10 of s -> idcg.
// Then all 1024 threads sweep the n*CUT contributing pairs.
// Pair algebra (validated round 2, absmax 0.0):
//   delta==0 unless i or j in top-10-by-o set T; for unordered pair {i,j} with
//   g_i != g_j: bce_ij + bce_ji = 2*softplus(o_lo - o_hi), hi = larger-s member.
__global__ __launch_bounds__(BLOCK)
void lambdarank_kernel(const float* __restrict__ og,
                       const float* __restrict__ sg,
                       float* __restrict__ out)
{
    __shared__ uint64_t wmax[2][2][GWAVES];   // [group][parity][wave-in-group]
    __shared__ float  top_ov[CUT];
    __shared__ int    top_oi[CUT];
    __shared__ float  top_gv[CUT];
    __shared__ float  sh_idcg;
    __shared__ double wave_part[NWAVE];

    const int tid  = threadIdx.x;
    const int lane = tid & 63;
    const int wid  = tid >> 6;
    const int grp  = (tid >= HALF) ? 1 : 0;
    const int gtid = tid - grp * HALF;        // 0..511
    const int gwid = gtid >> 6;               // 0..7

    // ---- load my group's array into registers as sortable keys ----
    const float* __restrict__ src = grp ? sg : og;
    uint64_t reg[PERT];
    #pragma unroll
    for (int k = 0; k < PERT; ++k) {
        int i = gtid + k * HALF;
        reg[k] = pack_key(src[i], i);
    }

    // ---- 10 masked argmax passes (both groups concurrently) ----
    float idcg = 0.f;                          // live only in tid==HALF
    for (int t = 0; t < CUT; ++t) {
        uint64_t m = 0;
        #pragma unroll
        for (int k = 0; k < PERT; ++k) m = (reg[k] > m) ? reg[k] : m;
        #pragma unroll
        for (int off = 32; off; off >>= 1) {
            uint64_t o = __shfl_xor((unsigned long long)m, off);
            m = (o > m) ? o : m;
        }
        const int par = t & 1;
        if (lane == 0) wmax[grp][par][gwid] = m;
        __syncthreads();
        uint64_t w = wmax[grp][par][0];
        #pragma unroll
        for (int q = 1; q < GWAVES; ++q) {
            uint64_t v = wmax[grp][par][q];
            w = (v > w) ? v : w;
        }
        if (tid == 0)    { top_ov[t] = key_val(w); top_oi[t] = key_idx(w); }
        if (tid == HALF) { idcg += (exp2f(key_val(w)) - 1.f) / log2f((float)(t + 2)); }
        #pragma unroll
        for (int k = 0; k < PERT; ++k) if (reg[k] == w) reg[k] = 0;  // deselect (keys unique)
    }
    if (tid == HALF) sh_idcg = idcg;
    __syncthreads();
    if (tid < CUT) top_gv[tid] = exp2f(sg[top_oi[tid]]) - 1.f;   // L2-warm reload
    __syncthreads();

    // ---- pair sweep: n items x 10 top items ----
    float t_ov[CUT], t_gv[CUT], t_disc[CUT];
    int   t_oi[CUT];
    #pragma unroll
    for (int t = 0; t < CUT; ++t) {
        t_ov[t]   = top_ov[t];
        t_gv[t]   = top_gv[t];
        t_oi[t]   = top_oi[t];
        t_disc[t] = 1.f / log2f((float)(t + 2));
    }
    const float inv_idcg = 1.f / sh_idcg;

    double acc = 0.0;
    #pragma unroll
    for (int k = 0; k < JPT; ++k) {
        const int j  = tid + k * BLOCK;
        const float oj = og[j];
        const float gj = exp2f(sg[j]) - 1.f;
        int pos = CUT; float discj = 0.f;     // static-indexed disc pick (no scratch)
        #pragma unroll
        for (int t = 0; t < CUT; ++t)
            if (t_oi[t] == j) { pos = t; discj = t_disc[t]; }
        #pragma unroll
        for (int t = 0; t < CUT; ++t) {
            const float oi = t_ov[t];
            const float dg = t_gv[t] - gj;            // sign(dg) == sign(s_i - s_j)
            const float dd = t_disc[t] - discj;
            const float delta = fabsf(dg * dd) * inv_idcg;
            const float darg  = copysignf(1.f, dg) * (oj - oi);   // o_lo - o_hi
            // softplus(x) = max(x,0) + ln2 * log2(1 + 2^(x*log2e))
            const float e  = exp2f(-fabsf(darg) * 1.4426950408889634f);
            const float l  = log2f(1.f + e);
            const float sp = fmaxf(darg, 0.f) + l * 0.6931471805599453f;
            if (t < pos && oi != oj)                  // count each pair once; mask o-ties
                acc += (double)(delta * (2.f * sp));
        }
    }

    // ---- block reduce ----
    #pragma unroll
    for (int off = 32; off; off >>= 1) acc += __shfl_down(acc, off);
    if (lane == 0) wave_part[wid] = acc;
    __syncthreads();
    if (tid == 0) {
        double tot = 0.0;
        #pragma unroll
        for (int w = 0; w < NWAVE; ++w) tot += wave_part[w];
        out[0] = (float)(tot / (double)NMAX);
    }
}

extern "C" void kernel_launch(void* const* d_in, const int* in_sizes, int n_in,
                              void* d_out, int out_size, void* d_ws, size_t ws_size,
                              hipStream_t stream) {
    const float* o = (const float*)d_in[0];
    const float* s = (const float*)d_in[1];
    float* out = (float*)d_out;
    lambdarank_kernel<<<dim3(1), dim3(BLOCK), 0, stream>>>(o, s, out);
}

// Round 5
// 74.884 us; speedup vs baseline: 2.6845x; 1.4516x over previous
//
#include <hip/hip_runtime.h>
#include <math.h>
#include <stdint.h>

#define CUT  10          // NDCG_CUTOFF
#define N    8192

// ---- ws layout (bytes) ----
//  [0,256)   double partials[32]
//  [256,296) float  top_ov[10]
//  [296,336) float  top_gv[10]
//  [336,340) float  inv_idcg
//  [344,384) int    top_oi[10]
#define WS_PART(ws) ((double*)(ws))
#define WS_OV(ws)   ((float*)((char*)(ws) + 256))
#define WS_GV(ws)   ((float*)((char*)(ws) + 296))
#define WS_INV(ws)  ((float*)((char*)(ws) + 336))
#define WS_OI(ws)   ((int*)((char*)(ws) + 344))

// Sortable key: monotone u32 of float in high bits, ~index low.
// max == max value; value ties break toward SMALLER index (stable argsort(-o)).
__device__ __forceinline__ uint64_t pack_key(float v, int i) {
    uint32_t fb = __float_as_uint(v);
    uint32_t k  = (fb & 0x80000000u) ? ~fb : (fb | 0x80000000u);
    return ((uint64_t)k << 32) | (uint32_t)~(uint32_t)i;
}
__device__ __forceinline__ float key_val(uint64_t key) {
    uint32_t k  = (uint32_t)(key >> 32);
    uint32_t fb = (k & 0x80000000u) ? (k & 0x7FFFFFFFu) : ~k;
    return __uint_as_float(fb);
}
__device__ __forceinline__ int key_idx(uint64_t key) {
    return (int)~(uint32_t)key;
}

// ================= K1: top-10 selection (1 block) =================
// Waves 0-7: top-10 of o (stable). Waves 8-15: top-10 of s -> idcg.
// f32 keys live in 16 VGPRs/thread; one __syncthreads per pass; previous
// winner is lazily deselected by its owning thread (exclusive slot).
#define B1    1024
#define HALF  512
#define PERT  (N / HALF)   // 16
#define GW    8            // waves per group

__global__ __launch_bounds__(B1, 4)
void k_select(const float* __restrict__ og, const float* __restrict__ sg,
              void* __restrict__ ws)
{
    __shared__ uint64_t wmax[2][2][GW];   // [group][parity][wave-in-group]
    __shared__ int      sh_oi[CUT];

    const int tid  = threadIdx.x;
    const int lane = tid & 63;
    const int grp  = tid >> 9;            // 0: o-array, 1: s-array
    const int gtid = tid & (HALF - 1);
    const int gwid = gtid >> 6;

    const float* __restrict__ src = grp ? sg : og;
    float vals[PERT];
    #pragma unroll
    for (int k = 0; k < PERT; ++k) vals[k] = src[gtid + k * HALF];

    float idcg = 0.f;                     // group-1: all threads, uniform
    int   w_idx_prev = -1;
    for (int t = 0; t < CUT; ++t) {
        // lazy deselect of previous winner (exactly one thread owns the slot)
        #pragma unroll
        for (int k = 0; k < PERT; ++k)
            if (gtid + k * HALF == w_idx_prev) vals[k] = -INFINITY;
        // local argmax; strict > with ascending k keeps smallest own index
        float bv = vals[0]; int bk = 0;
        #pragma unroll
        for (int k = 1; k < PERT; ++k)
            if (vals[k] > bv) { bv = vals[k]; bk = k; }
        uint64_t m = pack_key(bv, gtid + bk * HALF);
        #pragma unroll
        for (int off = 32; off; off >>= 1) {
            uint64_t o = __shfl_xor((unsigned long long)m, off);
            m = (o > m) ? o : m;
        }
        const int par = t & 1;            // parity dbuf: write t+1 lands after
        if (lane == 0) wmax[grp][par][gwid] = m;   // barrier t, readers of t-1 done
        __syncthreads();
        uint64_t w = wmax[grp][par][0];
        #pragma unroll
        for (int q = 1; q < GW; ++q) { uint64_t v = wmax[grp][par][q]; if (v > w) w = v; }
        const float wv = key_val(w);
        const int   wi = key_idx(w);
        if (grp == 0) {
            if (tid == 0) { WS_OV(ws)[t] = wv; WS_OI(ws)[t] = wi; sh_oi[t] = wi; }
        } else {
            idcg += (exp2f(wv) - 1.f) / log2f((float)(t + 2));
        }
        w_idx_prev = wi;
    }
    if (tid == HALF) WS_INV(ws)[0] = 1.f / idcg;
    __syncthreads();
    if (tid < CUT) WS_GV(ws)[tid] = exp2f(sg[sh_oi[tid]]) - 1.f;
}

// ================= K2: pair sweep (32 blocks x 256) =================
// Pair algebra (validated rounds 2+4, absmax 0.0):
//   delta==0 unless i or j in top-10-by-o set T; for unordered pair {i,j}
//   with g_i != g_j: bce_ij + bce_ji = 2*softplus(o_lo - o_hi),
//   hi = larger-s member (sign via dg = g_i - g_j, exp2 monotone).
// Pair {top_t, j} counted once: thread j counts slot t iff t < pos(j).
#define B2 256
#define G2 (N / B2)   // 32

__global__ __launch_bounds__(B2)
void k_sweep(const float* __restrict__ og, const float* __restrict__ sg,
             void* __restrict__ ws)
{
    __shared__ double wpart[B2 / 64];
    const int tid = threadIdx.x;
    const int j   = blockIdx.x * B2 + tid;

    float t_ov[CUT], t_gv[CUT], t_disc[CUT]; int t_oi[CUT];
    #pragma unroll
    for (int t = 0; t < CUT; ++t) {
        t_ov[t]   = WS_OV(ws)[t];
        t_gv[t]   = WS_GV(ws)[t];
        t_oi[t]   = WS_OI(ws)[t];
        t_disc[t] = 1.f / log2f((float)(t + 2));
    }
    const float inv_idcg = WS_INV(ws)[0];

    const float oj = og[j];
    const float gj = exp2f(sg[j]) - 1.f;
    int pos = CUT; float discj = 0.f;
    #pragma unroll
    for (int t = 0; t < CUT; ++t)
        if (t_oi[t] == j) { pos = t; discj = t_disc[t]; }

    double acc = 0.0;
    #pragma unroll
    for (int t = 0; t < CUT; ++t) {
        const float oi = t_ov[t];
        const float dg = t_gv[t] - gj;           // sign(dg) == sign(s_i - s_j)
        const float dd = t_disc[t] - discj;
        const float delta = fabsf(dg * dd) * inv_idcg;
        const float darg  = copysignf(1.f, dg) * (oj - oi);   // o_lo - o_hi
        const float e  = exp2f(-fabsf(darg) * 1.4426950408889634f);
        const float l  = log2f(1.f + e);
        const float sp = fmaxf(darg, 0.f) + l * 0.6931471805599453f;
        if (t < pos && oi != oj)
            acc += (double)(delta * (2.f * sp));
    }
    #pragma unroll
    for (int off = 32; off; off >>= 1) acc += __shfl_down(acc, off);
    const int lane = tid & 63, wid = tid >> 6;
    if (lane == 0) wpart[wid] = acc;
    __syncthreads();
    if (tid == 0) {
        double tot = 0.0;
        #pragma unroll
        for (int w = 0; w < B2 / 64; ++w) tot += wpart[w];
        WS_PART(ws)[blockIdx.x] = tot;
    }
}

// ================= K3: deterministic final sum =================
__global__ __launch_bounds__(64)
void k_final(void* __restrict__ ws, float* __restrict__ out)
{
    const int lane = threadIdx.x;
    double v = (lane < G2) ? WS_PART(ws)[lane] : 0.0;
    #pragma unroll
    for (int off = 32; off; off >>= 1) v += __shfl_down(v, off);
    if (lane == 0) out[0] = (float)(v / (double)N);
}

extern "C" void kernel_launch(void* const* d_in, const int* in_sizes, int n_in,
                              void* d_out, int out_size, void* d_ws, size_t ws_size,
                              hipStream_t stream) {
    const float* o = (const float*)d_in[0];
    const float* s = (const float*)d_in[1];
    float* out = (float*)d_out;
    k_select<<<dim3(1),  dim3(B1), 0, stream>>>(o, s, d_ws);
    k_sweep <<<dim3(G2), dim3(B2), 0, stream>>>(o, s, d_ws);
    k_final <<<dim3(1),  dim3(64), 0, stream>>>(d_ws, out);
}